// Round 8
// baseline (91.424 us; speedup 1.0000x reference)
//
#include <hip/hip_runtime.h>

typedef __attribute__((ext_vector_type(8))) short bf16x8;
typedef __attribute__((ext_vector_type(4))) float f32x4;
typedef unsigned int u32;
typedef unsigned short u16;

#define NROWS 8192
#define NDIM 128
#define NSTRIP 32                       /* column strips */
#define COLS_PER_STRIP (NROWS / NSTRIP) /* 256 */
#define BN 16                           /* cols per iteration */
#define WITERS (COLS_PER_STRIP / BN)    /* 16 */

#define SQRT_LOG2E 1.2011224087864498f     /* sqrt(log2(e)); S_scaled = S*log2e */
#define TWO_OVER_LOG2E 1.3862943611198906f /* 2/log2(e) */

__device__ __forceinline__ float hw_exp2(float x) {
  float r;
  asm("v_exp_f32 %0, %1" : "=v"(r) : "v"(x));
  return r;
}

// ---------------- convert fp32 -> bf16*sqrt(log2e) (+ fused pt_loss partial) --

__device__ __forceinline__ u16 f2bf(float x) {
  u32 u = __float_as_uint(x);
  u32 r = (u + 0x7fffu + ((u >> 16) & 1u)) >> 16; // RTNE
  return (u16)r;
}

__global__ __launch_bounds__(256) void esupcon_convert(
    const float* __restrict__ za, const float* __restrict__ zt,
    const float* __restrict__ w, u16* __restrict__ zabf,
    u16* __restrict__ ztbf, float* __restrict__ pt_part) {
  const int b = blockIdx.x, t = threadIdx.x;
  const bool tp = b >= 1024;
  const float* src = tp ? zt : za;
  u16* dst = tp ? ztbf : zabf;
  const int base = ((b & 1023) * 256 + t) * 4;
  float4 v = *reinterpret_cast<const float4*>(src + base);

  // pt partial from UNSCALED values
  const int k = base & (NDIM - 1); // 4 consecutive k, no row crossing
  float p = v.x * (w[NDIM + k + 0] - w[k + 0]) + v.y * (w[NDIM + k + 1] - w[k + 1]) +
            v.z * (w[NDIM + k + 2] - w[k + 2]) + v.w * (w[NDIM + k + 3] - w[k + 3]);
  if (tp) p = -p;

  ushort4 o;
  o.x = f2bf(v.x * SQRT_LOG2E);
  o.y = f2bf(v.y * SQRT_LOG2E);
  o.z = f2bf(v.z * SQRT_LOG2E);
  o.w = f2bf(v.w * SQRT_LOG2E);
  *reinterpret_cast<ushort4*>(dst + base) = o;

  __shared__ float red[256];
  red[t] = p;
  __syncthreads();
  for (int st = 128; st > 0; st >>= 1) {
    if (t < st) red[t] += red[t + st];
    __syncthreads();
  }
  if (t == 0) pt_part[b] = red[0];
}

// ---------------- stage 1: per-wave 64rows x 16cols/iter, no barriers --------

template <bool MASK>
__device__ __forceinline__ void compute_tile(
    const char* __restrict__ lA, const char* __restrict__ lT,
    const bf16x8 (&afA)[4][4], const bf16x8 (&afT)[4][4],
    float (&poss)[4][4], float (&negs)[4][4], float* __restrict__ diagv,
    int row0, int col0, int lane) {
  const int lc = lane & 15, kg = lane >> 4;
  const int colg = col0 + lc;

  // ---- pass 1: S_aa ----
  f32x4 accA[4] = {};
#pragma unroll
  for (int s = 0; s < 4; ++s) {
    const int off = (lc * 256 + s * 64 + kg * 16) ^ ((lc & 7) << 4);
    bf16x8 b = *reinterpret_cast<const bf16x8*>(lA + off);
#pragma unroll
    for (int rt = 0; rt < 4; ++rt)
      accA[rt] = __builtin_amdgcn_mfma_f32_16x16x32_bf16(afA[rt][s], b, accA[rt], 0, 0, 0);
  }
#pragma unroll
  for (int rt = 0; rt < 4; ++rt)
#pragma unroll
    for (int r = 0; r < 4; ++r) {
      float e = hw_exp2(accA[rt][r]);
      if (MASK && (row0 + rt * 16 + kg * 4 + r) == colg) e = 0.f;
      poss[rt][r] += e;
    }

  // ---- pass 2: S_tt and S_at (share the bT fragment) ----
  f32x4 accT[4] = {}, accX[4] = {};
#pragma unroll
  for (int s = 0; s < 4; ++s) {
    const int off = (lc * 256 + s * 64 + kg * 16) ^ ((lc & 7) << 4);
    bf16x8 b = *reinterpret_cast<const bf16x8*>(lT + off);
#pragma unroll
    for (int rt = 0; rt < 4; ++rt) {
      accT[rt] = __builtin_amdgcn_mfma_f32_16x16x32_bf16(afT[rt][s], b, accT[rt], 0, 0, 0);
      accX[rt] = __builtin_amdgcn_mfma_f32_16x16x32_bf16(afA[rt][s], b, accX[rt], 0, 0, 0);
    }
  }
#pragma unroll
  for (int rt = 0; rt < 4; ++rt)
#pragma unroll
    for (int r = 0; r < 4; ++r) {
      float ett = hw_exp2(accT[rt][r]);
      float vat = accX[rt][r];
      float eat = hw_exp2(vat);
      if (MASK) {
        const bool dia = (row0 + rt * 16 + kg * 4 + r) == colg;
        if (dia) {
          diagv[colg] = vat; // scaled by log2e; fixed in reduce1
          ett = 0.f;
          eat = 0.f;
        }
      }
      poss[rt][r] += ett;
      negs[rt][r] += eat;
    }
}

__global__ __launch_bounds__(64, 2) void esupcon_stage1(
    const u16* __restrict__ zabf, const u16* __restrict__ ztbf,
    float* __restrict__ pos_part, float* __restrict__ neg_part,
    float* __restrict__ diagv) {
  __shared__ __align__(16) char lds[2][8192]; // [buf][ A 4KB | T 4KB ]

  const int lane = threadIdx.x; // 0..63, one wave per block
  const int rg = blockIdx.x;    // row group of 64 (0..127)
  const int cs = blockIdx.y;    // column strip (0..NSTRIP-1)
  const int row0 = rg * 64;

  // A fragments for both matrices: 64 rows x K=128, in registers
  bf16x8 afA[4][4], afT[4][4]; // [rt][s]
  {
    const int rlo = lane & 15, kg = lane >> 4;
#pragma unroll
    for (int rt = 0; rt < 4; ++rt) {
      const u16* pa = zabf + (size_t)(row0 + rt * 16 + rlo) * NDIM + kg * 8;
      const u16* pt = ztbf + (size_t)(row0 + rt * 16 + rlo) * NDIM + kg * 8;
#pragma unroll
      for (int s = 0; s < 4; ++s) {
        afA[rt][s] = *reinterpret_cast<const bf16x8*>(pa + s * 32);
        afT[rt][s] = *reinterpret_cast<const bf16x8*>(pt + s * 32);
      }
    }
  }

  float poss[4][4] = {}, negs[4][4] = {};

  auto stage = [&](int buf, int it) {
    const size_t colbase = (size_t)(cs * COLS_PER_STRIP + it * BN) * NDIM;
    const char* gA = (const char*)(zabf + colbase);
    const char* gT = (const char*)(ztbf + colbase);
    char* dst = &lds[buf][0];
#pragma unroll
    for (int j = 0; j < 4; ++j) {
      const int y = j * 1024 + lane * 16;
      const int ysw = y ^ (((y >> 8) & 7) << 4); // involutive st-swizzle
      __builtin_amdgcn_global_load_lds(
          (const __attribute__((address_space(1))) u32*)(gA + ysw),
          (__attribute__((address_space(3))) u32*)(dst + j * 1024), 16, 0, 0);
    }
#pragma unroll
    for (int j = 0; j < 4; ++j) {
      const int y = j * 1024 + lane * 16;
      const int ysw = y ^ (((y >> 8) & 7) << 4);
      __builtin_amdgcn_global_load_lds(
          (const __attribute__((address_space(1))) u32*)(gT + ysw),
          (__attribute__((address_space(3))) u32*)(dst + 4096 + j * 1024), 16, 0, 0);
    }
  };

  stage(0, 0);
  int cur = 0;
  for (int it = 0; it < WITERS; ++it) {
    if (it + 1 < WITERS) {
      stage(cur ^ 1, it + 1); // prefetch next tile; stays in flight
      asm volatile("s_waitcnt vmcnt(8)" ::: "memory"); // current tile landed
    } else {
      asm volatile("s_waitcnt vmcnt(0)" ::: "memory");
    }
    __builtin_amdgcn_sched_barrier(0);

    const int col0 = cs * COLS_PER_STRIP + it * BN;
    const bool hasdiag = ((col0 >> 6) == rg); // wave-uniform
    if (hasdiag)
      compute_tile<true>(&lds[cur][0], &lds[cur][4096], afA, afT, poss, negs,
                         diagv, row0, col0, lane);
    else
      compute_tile<false>(&lds[cur][0], &lds[cur][4096], afA, afT, poss, negs,
                          diagv, row0, col0, lane);
    cur ^= 1;
  }

  // reduce over the 16 columns (lanes sharing lane>>4)
#pragma unroll
  for (int m = 1; m < 16; m <<= 1) {
#pragma unroll
    for (int rt = 0; rt < 4; ++rt)
#pragma unroll
      for (int r = 0; r < 4; ++r) {
        poss[rt][r] += __shfl_xor(poss[rt][r], m, 64);
        negs[rt][r] += __shfl_xor(negs[rt][r], m, 64);
      }
  }

  if ((lane & 15) == 0) {
    const int kg = lane >> 4;
#pragma unroll
    for (int rt = 0; rt < 4; ++rt)
#pragma unroll
      for (int r = 0; r < 4; ++r) {
        const int row = row0 + rt * 16 + kg * 4 + r;
        pos_part[(size_t)row * NSTRIP + cs] = poss[rt][r];
        neg_part[(size_t)row * NSTRIP + cs] = negs[rt][r];
      }
  }
}

// ---------------- parallel reduction, stage A: 32 blocks ----------------

__global__ __launch_bounds__(256) void esupcon_reduce1(
    const float* __restrict__ pos_part, const float* __restrict__ neg_part,
    const float* __restrict__ diagv, const float* __restrict__ pt_part,
    float* __restrict__ part_out /* [64]: 0..31 supcon, 32..63 pt */) {
  const int b = blockIdx.x, t = threadIdx.x;
  const int r = b * 256 + t; // one row per thread
  const f32x4* pp = reinterpret_cast<const f32x4*>(pos_part + (size_t)r * NSTRIP);
  const f32x4* np = reinterpret_cast<const f32x4*>(neg_part + (size_t)r * NSTRIP);
  float P = 0.f, Nn = 0.f;
#pragma unroll
  for (int s = 0; s < 8; ++s) {
    f32x4 a = pp[s], c = np[s];
    P += a[0] + a[1] + a[2] + a[3];
    Nn += c[0] + c[1] + c[2] + c[3];
  }
  float sc = -logf(P) + logf(Nn) + TWO_OVER_LOG2E * diagv[r];
  float pt = (t < 64) ? pt_part[b * 64 + t] : 0.f;

  __shared__ float s1[256], s2[256];
  s1[t] = sc;
  s2[t] = pt;
  __syncthreads();
  for (int st = 128; st > 0; st >>= 1) {
    if (t < st) {
      s1[t] += s1[t + st];
      s2[t] += s2[t + st];
    }
    __syncthreads();
  }
  if (t == 0) {
    part_out[b] = s1[0];
    part_out[32 + b] = s2[0];
  }
}

// ---------------- final reduction: 1 block, 1 wave ----------------

__global__ __launch_bounds__(64) void esupcon_reduce2(
    const float* __restrict__ part_out, float* __restrict__ out) {
  const int t = threadIdx.x;
  float sc = (t < 32) ? part_out[t] : 0.f;
  float pt = (t < 32) ? part_out[32 + t] : 0.f;
#pragma unroll
  for (int m = 1; m < 64; m <<= 1) {
    sc += __shfl_xor(sc, m, 64);
    pt += __shfl_xor(pt, m, 64);
  }
  if (t == 0) {
    const float pt_loss = pt / (float)NROWS;
    out[0] = ((float)NROWS * (float)NDIM / ((float)NROWS + 2.0f)) * (pt_loss + sc);
  }
}

// ---------------- launcher ----------------

extern "C" void kernel_launch(void* const* d_in, const int* in_sizes, int n_in,
                              void* d_out, int out_size, void* d_ws, size_t ws_size,
                              hipStream_t stream) {
  const float* za = (const float*)d_in[0];
  const float* zt = (const float*)d_in[1];
  const float* w = (const float*)d_in[2];
  float* out = (float*)d_out;

  char* ws = (char*)d_ws;
  u16* zabf = (u16*)ws;                               // 2 MB
  u16* ztbf = (u16*)(ws + (size_t)(1 << 21));         // 2 MB
  float* pos_part = (float*)(ws + (size_t)(2 << 21)); // 1 MB (8192*32)
  float* neg_part = (float*)(ws + (size_t)(2 << 21) + (1 << 20));
  float* diagv = (float*)(ws + (size_t)(2 << 21) + (2 << 20));               // 32 KB
  float* pt_part = (float*)(ws + (size_t)(2 << 21) + (2 << 20) + (1 << 15)); // 8 KB
  float* part_out = (float*)(ws + (size_t)(2 << 21) + (2 << 20) + (1 << 15) + (1 << 13));

  esupcon_convert<<<dim3(2048), dim3(256), 0, stream>>>(za, zt, w, zabf, ztbf, pt_part);
  esupcon_stage1<<<dim3(NROWS / 64, NSTRIP), dim3(64), 0, stream>>>(
      zabf, ztbf, pos_part, neg_part, diagv);
  esupcon_reduce1<<<dim3(32), dim3(256), 0, stream>>>(pos_part, neg_part, diagv,
                                                      pt_part, part_out);
  esupcon_reduce2<<<dim3(1), dim3(64), 0, stream>>>(part_out, out);
}

// Round 10
// 80.810 us; speedup vs baseline: 1.1313x; 1.1313x over previous
//
#include <hip/hip_runtime.h>

typedef __attribute__((ext_vector_type(8))) short bf16x8;
typedef __attribute__((ext_vector_type(4))) float f32x4;
typedef unsigned int u32;
typedef unsigned short u16;

#define NROWS 8192
#define NDIM 128
#define NSTRIP 16                       /* column strips */
#define COLS_PER_STRIP (NROWS / NSTRIP) /* 512 */
#define BN 16                           /* cols per iteration */
#define WITERS (COLS_PER_STRIP / BN)    /* 32 */

#define SQRT_LOG2E 1.2011224087864498f     /* sqrt(log2(e)); S_scaled = S*log2e */
#define TWO_OVER_LOG2E 1.3862943611198906f /* 2/log2(e) */

__device__ __forceinline__ float hw_exp2(float x) {
  float r;
  asm("v_exp_f32 %0, %1" : "=v"(r) : "v"(x));
  return r;
}

// ---------------- convert fp32 -> bf16*sqrt(log2e) (+ fused pt_loss partial) --

__device__ __forceinline__ u16 f2bf(float x) {
  u32 u = __float_as_uint(x);
  u32 r = (u + 0x7fffu + ((u >> 16) & 1u)) >> 16; // RTNE
  return (u16)r;
}

__global__ __launch_bounds__(256) void esupcon_convert(
    const float* __restrict__ za, const float* __restrict__ zt,
    const float* __restrict__ w, u16* __restrict__ zabf,
    u16* __restrict__ ztbf, float* __restrict__ pt_part) {
  const int b = blockIdx.x, t = threadIdx.x;
  const bool tp = b >= 1024;
  const float* src = tp ? zt : za;
  u16* dst = tp ? ztbf : zabf;
  const int base = ((b & 1023) * 256 + t) * 4;
  float4 v = *reinterpret_cast<const float4*>(src + base);

  // pt partial from UNSCALED values
  const int k = base & (NDIM - 1); // 4 consecutive k, no row crossing
  float p = v.x * (w[NDIM + k + 0] - w[k + 0]) + v.y * (w[NDIM + k + 1] - w[k + 1]) +
            v.z * (w[NDIM + k + 2] - w[k + 2]) + v.w * (w[NDIM + k + 3] - w[k + 3]);
  if (tp) p = -p;

  ushort4 o;
  o.x = f2bf(v.x * SQRT_LOG2E);
  o.y = f2bf(v.y * SQRT_LOG2E);
  o.z = f2bf(v.z * SQRT_LOG2E);
  o.w = f2bf(v.w * SQRT_LOG2E);
  *reinterpret_cast<ushort4*>(dst + base) = o;

  __shared__ float red[256];
  red[t] = p;
  __syncthreads();
  for (int st = 128; st > 0; st >>= 1) {
    if (t < st) red[t] += red[t + st];
    __syncthreads();
  }
  if (t == 0) pt_part[b] = red[0];
}

// ---------------- stage 1: per-wave 64rows x 16cols/iter, no barriers --------
// Identical to the round-2 passing kernel except: cs comes from blockIdx.x and
// rg from blockIdx.y, so XCD (= linear dispatch id & 7 = blockIdx.x & 7) is
// determined by the column strip -> each XCD's B working set is 2 panels
// (512 KB), L2-resident, instead of all 16 (8 MB, L2-thrashing).

template <bool MASK>
__device__ __forceinline__ void compute_tile(
    const char* __restrict__ lA, const char* __restrict__ lT,
    const bf16x8 (&afA)[4][4], const bf16x8 (&afT)[4][4],
    float (&poss)[4][4], float (&negs)[4][4], float* __restrict__ diagv,
    int row0, int col0, int lane) {
  const int lc = lane & 15, kg = lane >> 4;
  const int colg = col0 + lc;

  // ---- pass 1: S_aa ----
  f32x4 accA[4] = {};
#pragma unroll
  for (int s = 0; s < 4; ++s) {
    const int off = (lc * 256 + s * 64 + kg * 16) ^ ((lc & 7) << 4);
    bf16x8 b = *reinterpret_cast<const bf16x8*>(lA + off);
#pragma unroll
    for (int rt = 0; rt < 4; ++rt)
      accA[rt] = __builtin_amdgcn_mfma_f32_16x16x32_bf16(afA[rt][s], b, accA[rt], 0, 0, 0);
  }
#pragma unroll
  for (int rt = 0; rt < 4; ++rt)
#pragma unroll
    for (int r = 0; r < 4; ++r) {
      float e = hw_exp2(accA[rt][r]);
      if (MASK && (row0 + rt * 16 + kg * 4 + r) == colg) e = 0.f;
      poss[rt][r] += e;
    }

  // ---- pass 2: S_tt and S_at (share the bT fragment) ----
  f32x4 accT[4] = {}, accX[4] = {};
#pragma unroll
  for (int s = 0; s < 4; ++s) {
    const int off = (lc * 256 + s * 64 + kg * 16) ^ ((lc & 7) << 4);
    bf16x8 b = *reinterpret_cast<const bf16x8*>(lT + off);
#pragma unroll
    for (int rt = 0; rt < 4; ++rt) {
      accT[rt] = __builtin_amdgcn_mfma_f32_16x16x32_bf16(afT[rt][s], b, accT[rt], 0, 0, 0);
      accX[rt] = __builtin_amdgcn_mfma_f32_16x16x32_bf16(afA[rt][s], b, accX[rt], 0, 0, 0);
    }
  }
#pragma unroll
  for (int rt = 0; rt < 4; ++rt)
#pragma unroll
    for (int r = 0; r < 4; ++r) {
      float ett = hw_exp2(accT[rt][r]);
      float vat = accX[rt][r];
      float eat = hw_exp2(vat);
      if (MASK) {
        const bool dia = (row0 + rt * 16 + kg * 4 + r) == colg;
        if (dia) {
          diagv[colg] = vat; // scaled by log2e; fixed in reduce1
          ett = 0.f;
          eat = 0.f;
        }
      }
      poss[rt][r] += ett;
      negs[rt][r] += eat;
    }
}

__global__ __launch_bounds__(64, 2) void esupcon_stage1(
    const u16* __restrict__ zabf, const u16* __restrict__ ztbf,
    float* __restrict__ pos_part, float* __restrict__ neg_part,
    float* __restrict__ diagv) {
  __shared__ __align__(16) char lds[2][8192]; // [buf][ A 4KB | T 4KB ]

  const int lane = threadIdx.x; // 0..63, one wave per block
  const int cs = blockIdx.x;    // column strip (0..15)  -> fixes XCD affinity
  const int rg = blockIdx.y;    // row group of 64 (0..127)
  const int row0 = rg * 64;

  // A fragments for both matrices: 64 rows x K=128, in registers
  bf16x8 afA[4][4], afT[4][4]; // [rt][s]
  {
    const int rlo = lane & 15, kg = lane >> 4;
#pragma unroll
    for (int rt = 0; rt < 4; ++rt) {
      const u16* pa = zabf + (size_t)(row0 + rt * 16 + rlo) * NDIM + kg * 8;
      const u16* pt = ztbf + (size_t)(row0 + rt * 16 + rlo) * NDIM + kg * 8;
#pragma unroll
      for (int s = 0; s < 4; ++s) {
        afA[rt][s] = *reinterpret_cast<const bf16x8*>(pa + s * 32);
        afT[rt][s] = *reinterpret_cast<const bf16x8*>(pt + s * 32);
      }
    }
  }

  float poss[4][4] = {}, negs[4][4] = {};

  auto stage = [&](int buf, int it) {
    const size_t colbase = (size_t)(cs * COLS_PER_STRIP + it * BN) * NDIM;
    const char* gA = (const char*)(zabf + colbase);
    const char* gT = (const char*)(ztbf + colbase);
    char* dst = &lds[buf][0];
#pragma unroll
    for (int j = 0; j < 4; ++j) {
      const int y = j * 1024 + lane * 16;
      const int ysw = y ^ (((y >> 8) & 7) << 4); // involutive st-swizzle
      __builtin_amdgcn_global_load_lds(
          (const __attribute__((address_space(1))) u32*)(gA + ysw),
          (__attribute__((address_space(3))) u32*)(dst + j * 1024), 16, 0, 0);
    }
#pragma unroll
    for (int j = 0; j < 4; ++j) {
      const int y = j * 1024 + lane * 16;
      const int ysw = y ^ (((y >> 8) & 7) << 4);
      __builtin_amdgcn_global_load_lds(
          (const __attribute__((address_space(1))) u32*)(gT + ysw),
          (__attribute__((address_space(3))) u32*)(dst + 4096 + j * 1024), 16, 0, 0);
    }
  };

  stage(0, 0);
  int cur = 0;
  for (int it = 0; it < WITERS; ++it) {
    if (it + 1 < WITERS) {
      stage(cur ^ 1, it + 1); // prefetch next tile; stays in flight
      asm volatile("s_waitcnt vmcnt(8)" ::: "memory"); // current tile landed
    } else {
      asm volatile("s_waitcnt vmcnt(0)" ::: "memory");
    }
    __builtin_amdgcn_sched_barrier(0);

    const int col0 = cs * COLS_PER_STRIP + it * BN;
    const bool hasdiag = ((col0 >> 6) == rg); // wave-uniform
    if (hasdiag)
      compute_tile<true>(&lds[cur][0], &lds[cur][4096], afA, afT, poss, negs,
                         diagv, row0, col0, lane);
    else
      compute_tile<false>(&lds[cur][0], &lds[cur][4096], afA, afT, poss, negs,
                          diagv, row0, col0, lane);
    cur ^= 1;
  }

  // reduce over the 16 columns (lanes sharing lane>>4)
#pragma unroll
  for (int m = 1; m < 16; m <<= 1) {
#pragma unroll
    for (int rt = 0; rt < 4; ++rt)
#pragma unroll
      for (int r = 0; r < 4; ++r) {
        poss[rt][r] += __shfl_xor(poss[rt][r], m, 64);
        negs[rt][r] += __shfl_xor(negs[rt][r], m, 64);
      }
  }

  if ((lane & 15) == 0) {
    const int kg = lane >> 4;
#pragma unroll
    for (int rt = 0; rt < 4; ++rt)
#pragma unroll
      for (int r = 0; r < 4; ++r) {
        const int row = row0 + rt * 16 + kg * 4 + r;
        pos_part[(size_t)row * NSTRIP + cs] = poss[rt][r];
        neg_part[(size_t)row * NSTRIP + cs] = negs[rt][r];
      }
  }
}

// ---------------- parallel reduction, stage A: 32 blocks ----------------

__global__ __launch_bounds__(256) void esupcon_reduce1(
    const float* __restrict__ pos_part, const float* __restrict__ neg_part,
    const float* __restrict__ diagv, const float* __restrict__ pt_part,
    float* __restrict__ part_out /* [64]: 0..31 supcon, 32..63 pt */) {
  const int b = blockIdx.x, t = threadIdx.x;
  const int r = b * 256 + t; // one row per thread
  const f32x4* pp = reinterpret_cast<const f32x4*>(pos_part + (size_t)r * NSTRIP);
  const f32x4* np = reinterpret_cast<const f32x4*>(neg_part + (size_t)r * NSTRIP);
  float P = 0.f, Nn = 0.f;
#pragma unroll
  for (int s = 0; s < 4; ++s) {
    f32x4 a = pp[s], c = np[s];
    P += a[0] + a[1] + a[2] + a[3];
    Nn += c[0] + c[1] + c[2] + c[3];
  }
  float sc = -logf(P) + logf(Nn) + TWO_OVER_LOG2E * diagv[r];
  float pt = (t < 64) ? pt_part[b * 64 + t] : 0.f;

  __shared__ float s1[256], s2[256];
  s1[t] = sc;
  s2[t] = pt;
  __syncthreads();
  for (int st = 128; st > 0; st >>= 1) {
    if (t < st) {
      s1[t] += s1[t + st];
      s2[t] += s2[t + st];
    }
    __syncthreads();
  }
  if (t == 0) {
    part_out[b] = s1[0];
    part_out[32 + b] = s2[0];
  }
}

// ---------------- final reduction: 1 block, 1 wave ----------------

__global__ __launch_bounds__(64) void esupcon_reduce2(
    const float* __restrict__ part_out, float* __restrict__ out) {
  const int t = threadIdx.x;
  float sc = (t < 32) ? part_out[t] : 0.f;
  float pt = (t < 32) ? part_out[32 + t] : 0.f;
#pragma unroll
  for (int m = 1; m < 64; m <<= 1) {
    sc += __shfl_xor(sc, m, 64);
    pt += __shfl_xor(pt, m, 64);
  }
  if (t == 0) {
    const float pt_loss = pt / (float)NROWS;
    out[0] = ((float)NROWS * (float)NDIM / ((float)NROWS + 2.0f)) * (pt_loss + sc);
  }
}

// ---------------- launcher ----------------

extern "C" void kernel_launch(void* const* d_in, const int* in_sizes, int n_in,
                              void* d_out, int out_size, void* d_ws, size_t ws_size,
                              hipStream_t stream) {
  const float* za = (const float*)d_in[0];
  const float* zt = (const float*)d_in[1];
  const float* w = (const float*)d_in[2];
  float* out = (float*)d_out;

  char* ws = (char*)d_ws;
  u16* zabf = (u16*)ws;                               // 2 MB
  u16* ztbf = (u16*)(ws + (size_t)(1 << 21));         // 2 MB
  float* pos_part = (float*)(ws + (size_t)(2 << 21)); // 512 KB (8192*16)
  float* neg_part = (float*)(ws + (size_t)(2 << 21) + (1 << 20));
  float* diagv = (float*)(ws + (size_t)(2 << 21) + (2 << 20));               // 32 KB
  float* pt_part = (float*)(ws + (size_t)(2 << 21) + (2 << 20) + (1 << 15)); // 8 KB
  float* part_out = (float*)(ws + (size_t)(2 << 21) + (2 << 20) + (1 << 15) + (1 << 13));

  esupcon_convert<<<dim3(2048), dim3(256), 0, stream>>>(za, zt, w, zabf, ztbf, pt_part);
  esupcon_stage1<<<dim3(NSTRIP, NROWS / 64), dim3(64), 0, stream>>>(
      zabf, ztbf, pos_part, neg_part, diagv);
  esupcon_reduce1<<<dim3(32), dim3(256), 0, stream>>>(pos_part, neg_part, diagv,
                                                      pt_part, part_out);
  esupcon_reduce2<<<dim3(1), dim3(64), 0, stream>>>(part_out, out);
}